// Round 12
// baseline (152.581 us; speedup 1.0000x reference)
//
#include <hip/hip_runtime.h>
#include <hip/hip_bf16.h>

#define IN_CH 256
#define OUT_CH 128
#define BKT_SHIFT 7                 // 128 dst nodes per bucket
#define BKT_SIZE 128
#define MAXNB 1024                  // bucket-count cap
#define K3_CHUNK 8192
#define MAXBLK 256                  // bin blocks cap
#define BATCH 3072                  // k4 records per batch (6 regs * 512 threads)
#define CAPP 4096                   // k4 padded LDS capacity (BATCH + 128*7 <= CAPP)

using bf16x8 = __attribute__((ext_vector_type(8))) __bf16;
using f32x16 = __attribute__((ext_vector_type(16))) float;
using f32x4  = __attribute__((ext_vector_type(4))) float;
using f32x2  = __attribute__((ext_vector_type(2))) float;

__device__ __forceinline__ unsigned int f2bf(float f) {
    union { float f; unsigned u; } v; v.f = f;
    unsigned r = v.u + 0x7fffu + ((v.u >> 16) & 1u);
    return r >> 16;
}
__device__ __forceinline__ float bf2f(unsigned short u) {
    union { unsigned u; float f; } v; v.u = ((unsigned)u) << 16;
    return v.f;
}

// ---------------- prep_w: W (f32 [128][256]) -> bf16 MFMA B-fragment order ----------------
__global__ void __launch_bounds__(256) prep_w(const float* __restrict__ W,
                                              unsigned short* __restrict__ Wfrag) {
    const int flat = blockIdx.x * 256 + threadIdx.x;  // 0..4095
    const int l = flat & 63;
    const int ks = (flat >> 6) & 15;
    const int c = flat >> 10;
    const int row = c * 32 + (l & 31);
    const int col0 = ks * 16 + 8 * (l >> 5);
    const float* src = W + (size_t)row * IN_CH + col0;
    uint4 o;
    o.x = f2bf(src[0]) | (f2bf(src[1]) << 16);
    o.y = f2bf(src[2]) | (f2bf(src[3]) << 16);
    o.z = f2bf(src[4]) | (f2bf(src[5]) << 16);
    o.w = f2bf(src[6]) | (f2bf(src[7]) << 16);
    *reinterpret_cast<uint4*>(Wfrag + (size_t)flat * 8) = o;
}

// ---------------- linear: h = bf16(x @ W.T + b); Wfrag staged in LDS ----------------
// 512 threads = 8 waves; wave w owns rows [node0 + 32w, +32), all 128 cols.
__global__ void __launch_bounds__(512) linear_mfma(
    const float* __restrict__ x, const unsigned short* __restrict__ Wfrag,
    const float* __restrict__ b, unsigned short* __restrict__ h, int n_nodes) {
    __shared__ uint4 wlds[4096];     // 64 KB: full Wfrag in fragment order
    const int tid = threadIdx.x;
    const int w = tid >> 6, l = tid & 63;
    const int l31 = l & 31, lh = l >> 5;
    const int node0 = blockIdx.x * 256 + w * 32;

    // stage Wfrag -> LDS (coalesced, L2-resident source)
    {
        const uint4* wfg = reinterpret_cast<const uint4*>(Wfrag);
#pragma unroll
        for (int j = 0; j < 8; ++j) wlds[j * 512 + tid] = wfg[j * 512 + tid];
    }
    __syncthreads();

    int arow = node0 + l31;
    if (arow > n_nodes - 1) arow = n_nodes - 1;
    const float* xrow = x + (size_t)arow * IN_CH + 8 * lh;

    f32x16 acc0 = {}, acc1 = {}, acc2 = {}, acc3 = {};

#pragma unroll 4
    for (int ks = 0; ks < 16; ++ks) {
        float4 a0 = *reinterpret_cast<const float4*>(xrow + ks * 16);
        float4 a1 = *reinterpret_cast<const float4*>(xrow + ks * 16 + 4);
        bf16x8 af;
        af[0] = (__bf16)a0.x; af[1] = (__bf16)a0.y;
        af[2] = (__bf16)a0.z; af[3] = (__bf16)a0.w;
        af[4] = (__bf16)a1.x; af[5] = (__bf16)a1.y;
        af[6] = (__bf16)a1.z; af[7] = (__bf16)a1.w;

        uint4 bw0 = wlds[(0 * 16 + ks) * 64 + l];
        uint4 bw1 = wlds[(1 * 16 + ks) * 64 + l];
        uint4 bw2 = wlds[(2 * 16 + ks) * 64 + l];
        uint4 bw3 = wlds[(3 * 16 + ks) * 64 + l];

        acc0 = __builtin_amdgcn_mfma_f32_32x32x16_bf16(af, __builtin_bit_cast(bf16x8, bw0), acc0, 0, 0, 0);
        acc1 = __builtin_amdgcn_mfma_f32_32x32x16_bf16(af, __builtin_bit_cast(bf16x8, bw1), acc1, 0, 0, 0);
        acc2 = __builtin_amdgcn_mfma_f32_32x32x16_bf16(af, __builtin_bit_cast(bf16x8, bw2), acc2, 0, 0, 0);
        acc3 = __builtin_amdgcn_mfma_f32_32x32x16_bf16(af, __builtin_bit_cast(bf16x8, bw3), acc3, 0, 0, 0);
    }

    const float bias0 = b[0 + l31], bias1 = b[32 + l31], bias2 = b[64 + l31], bias3 = b[96 + l31];
#pragma unroll
    for (int reg = 0; reg < 16; ++reg) {
        const int r = (reg & 3) + 8 * (reg >> 2) + 4 * lh;
        const int node = node0 + r;
        if (node < n_nodes) {
            unsigned short* hp = h + (size_t)node * OUT_CH;
            __bf16 t0 = (__bf16)(acc0[reg] + bias0);
            __bf16 t1 = (__bf16)(acc1[reg] + bias1);
            __bf16 t2 = (__bf16)(acc2[reg] + bias2);
            __bf16 t3 = (__bf16)(acc3[reg] + bias3);
            hp[0 + l31]  = __builtin_bit_cast(unsigned short, t0);
            hp[32 + l31] = __builtin_bit_cast(unsigned short, t1);
            hp[64 + l31] = __builtin_bit_cast(unsigned short, t2);
            hp[96 + l31] = __builtin_bit_cast(unsigned short, t3);
        }
    }
}

// ---------------- K1: per-block bucket histogram (LDS, no global atomics) ----------------
__global__ void __launch_bounds__(512) k1_hist(
    const int* __restrict__ edge_dst, int* __restrict__ bh, int n_edges, int nb) {
    __shared__ int hist[MAXNB];
    const int t = threadIdx.x;
    const int blk = blockIdx.x;
    for (int i = t; i < MAXNB; i += 512) hist[i] = 0;
    __syncthreads();
    const int base = blk * K3_CHUNK;
#pragma unroll
    for (int j = 0; j < K3_CHUNK / 512; ++j) {
        int e = base + j * 512 + t;
        if (e < n_edges) atomicAdd(&hist[edge_dst[e] >> BKT_SHIFT], 1);
    }
    __syncthreads();
    for (int i = t; i < nb; i += 512) bh[i * MAXBLK + blk] = hist[i];
}

// ---------------- K2a: per-bucket exclusive scan over blocks ----------------
__global__ void __launch_bounds__(256) k2a_scan_cols(
    const int* __restrict__ bh, int* __restrict__ offs, int* __restrict__ total,
    int nblk) {
    __shared__ int sd[256];
    const int t = threadIdx.x;
    const int bkt = blockIdx.x;
    int val = (t < nblk) ? bh[bkt * MAXBLK + t] : 0;
    sd[t] = val;
    __syncthreads();
    for (int s = 1; s < 256; s <<= 1) {
        int y = (t >= s) ? sd[t - s] : 0;
        __syncthreads();
        sd[t] += y;
        __syncthreads();
    }
    offs[bkt * MAXBLK + t] = sd[t] - val;
    if (t == 255) total[bkt] = sd[255];
}

// ---------------- K2b: exclusive scan over bucket totals -> base ----------------
__global__ void __launch_bounds__(256) k2b_scan_base(
    const int* __restrict__ total, int* __restrict__ base, int nb) {
    __shared__ int sd[256];
    const int t = threadIdx.x;
    int v[4];
    int loc = 0;
#pragma unroll
    for (int k = 0; k < 4; ++k) {
        int idx = t * 4 + k;
        v[k] = (idx < nb) ? total[idx] : 0;
        loc += v[k];
    }
    sd[t] = loc;
    __syncthreads();
    for (int s = 1; s < 256; s <<= 1) {
        int y = (t >= s) ? sd[t - s] : 0;
        __syncthreads();
        sd[t] += y;
        __syncthreads();
    }
    int run = sd[t] - loc;
#pragma unroll
    for (int k = 0; k < 4; ++k) {
        int idx = t * 4 + k;
        if (idx < nb) base[idx] = run;
        run += v[k];
    }
    if (t == 255) base[nb] = sd[255];
}

// ---------------- K3: chunk counting-sort by bucket, coalesced record write ----------------
// record u64: [w_bf16:48-63 | bucket:24-33 | dst&127:17-23 | src:0-16]
__global__ void __launch_bounds__(512) k3_bin(
    const int* __restrict__ edge_src, const int* __restrict__ edge_dst,
    const float* __restrict__ edge_weight,
    const int* __restrict__ offs, const int* __restrict__ base,
    unsigned long long* __restrict__ records, int n_edges, int nb) {
    __shared__ unsigned long long staged[K3_CHUNK];
    __shared__ int hist[MAXNB];
    __shared__ int cur[MAXNB];
    __shared__ int gbase[MAXNB];
    __shared__ int sd[512];

    const int t = threadIdx.x;
    const int blk = blockIdx.x;
    const int ebase = blk * K3_CHUNK;
    const int count = min(K3_CHUNK, n_edges - ebase);

    for (int i = t; i < MAXNB; i += 512) hist[i] = 0;
    __syncthreads();
#pragma unroll
    for (int j = 0; j < K3_CHUNK / 512; ++j) {
        int e = ebase + j * 512 + t;
        if (e < n_edges) atomicAdd(&hist[edge_dst[e] >> BKT_SHIFT], 1);
    }
    __syncthreads();
    int h0 = hist[2 * t], h1 = hist[2 * t + 1];
    int loc = h0 + h1;
    sd[t] = loc;
    __syncthreads();
    for (int s = 1; s < 512; s <<= 1) {
        int y = (t >= s) ? sd[t - s] : 0;
        __syncthreads();
        sd[t] += y;
        __syncthreads();
    }
    int excl = sd[t] - loc;
    cur[2 * t] = excl;
    cur[2 * t + 1] = excl + h0;
    if (2 * t < nb)     gbase[2 * t]     = base[2 * t]     + offs[(2 * t) * MAXBLK + blk]     - excl;
    if (2 * t + 1 < nb) gbase[2 * t + 1] = base[2 * t + 1] + offs[(2 * t + 1) * MAXBLK + blk] - (excl + h0);
    __syncthreads();
#pragma unroll
    for (int j = 0; j < K3_CHUNK / 512; ++j) {
        int e = ebase + j * 512 + t;
        if (e < n_edges) {
            int d = edge_dst[e];
            int bkt = d >> BKT_SHIFT;
            unsigned int wbits = f2bf(edge_weight[e]);   // bf16 bits
            unsigned long long rec = ((unsigned long long)wbits << 48) |
                                     ((unsigned long long)bkt << 24) |
                                     ((unsigned long long)(d & (BKT_SIZE - 1)) << 17) |
                                     (unsigned int)edge_src[e];
            int pos = atomicAdd(&cur[bkt], 1);
            staged[pos] = rec;
        }
    }
    __syncthreads();
    for (int i = t; i < count; i += 512) {
        unsigned long long r = staged[i];
        int bkt = (int)((r >> 24) & 1023u);
        records[gbase[bkt] + i] = r;
    }
}

// ---------------- K4: per-bucket dst-sort (regs->LDS, 8-padded) + 16-deep gather -------
// block = 512 threads = 8 waves; wave w owns 16 dst rows; lane owns channels 2l, 2l+1.
__global__ void __launch_bounds__(512) k4_agg(
    const unsigned short* __restrict__ h, const unsigned long long* __restrict__ records,
    const int* __restrict__ base, float* __restrict__ out, int n_nodes) {
    __shared__ unsigned long long sorted[CAPP];   // 32 KB
    __shared__ int hist[BKT_SIZE];
    __shared__ int cur[BKT_SIZE];
    __shared__ int pstart[BKT_SIZE];
    __shared__ int sd[BKT_SIZE];
    __shared__ int ptot;

    const int t = threadIdx.x;
    const int bkt = blockIdx.x;
    const int w = t >> 6, lane = t & 63;
    const int rbeg = base[bkt], rend = base[bkt + 1];

    float acc[16][2];
#pragma unroll
    for (int d = 0; d < 16; ++d) { acc[d][0] = 0.f; acc[d][1] = 0.f; }

    for (int b0 = rbeg; b0 < rend; b0 += BATCH) {
        const int cnt = min(BATCH, rend - b0);
        __syncthreads();  // previous batch fully consumed
        // stage records into registers (coalesced, read global exactly once)
        unsigned long long r[6];
#pragma unroll
        for (int j = 0; j < 6; ++j) {
            const int o = j * 512 + t;
            r[j] = (o < cnt) ? records[b0 + o] : 0ull;
        }
        if (t < BKT_SIZE) hist[t] = 0;
        __syncthreads();
        // histogram by dst-low
#pragma unroll
        for (int j = 0; j < 6; ++j) {
            const int o = j * 512 + t;
            if (o < cnt) atomicAdd(&hist[(unsigned)(r[j] >> 17) & 127u], 1);
        }
        __syncthreads();
        // exclusive scan of ceil8(hist) -> 8-aligned segment starts
        if (t < BKT_SIZE) sd[t] = (hist[t] + 7) & ~7;
        __syncthreads();
        for (int s = 1; s < BKT_SIZE; s <<= 1) {
            int y = 0;
            if (t < BKT_SIZE && t >= s) y = sd[t - s];
            __syncthreads();
            if (t < BKT_SIZE) sd[t] += y;
            __syncthreads();
        }
        if (t < BKT_SIZE) {
            const int e = sd[t] - ((hist[t] + 7) & ~7);
            pstart[t] = e;
            cur[t] = e;
        }
        if (t == BKT_SIZE - 1) ptot = sd[BKT_SIZE - 1];
        __syncthreads();
        // zero the padded region (pad records: w=0, src=0 -> contribute nothing)
        const int pt = ptot;
        for (int i = t; i < pt; i += 512) sorted[i] = 0ull;
        __syncthreads();
        // scatter into dst-sorted order
#pragma unroll
        for (int j = 0; j < 6; ++j) {
            const int o = j * 512 + t;
            if (o < cnt) {
                const int dl = (int)((unsigned)(r[j] >> 17) & 127u);
                const int pos = atomicAdd(&cur[dl], 1);
                sorted[pos] = r[j];
            }
        }
        __syncthreads();
        // aggregate: wave w handles dl = w*16+d; 16 gathers in flight, 8-tail
#pragma unroll
        for (int d = 0; d < 16; ++d) {
            const int dl = w * 16 + d;
            const int s0 = pstart[dl];
            const int s1p = s0 + ((hist[dl] + 7) & ~7);   // padded end
            float a0 = 0.f, a1 = 0.f;
            int i = s0;
            for (; i + 16 <= s1p; i += 16) {
                unsigned int hv[16];
                float wt[16];
#pragma unroll
                for (int j = 0; j < 16; ++j) {
                    const unsigned long long rr = sorted[i + j];   // uniform broadcast
                    const unsigned lo = __builtin_amdgcn_readfirstlane((unsigned)rr);
                    const unsigned hi = __builtin_amdgcn_readfirstlane((unsigned)(rr >> 32));
                    wt[j] = __builtin_bit_cast(float, hi & 0xFFFF0000u);
                    const unsigned* hp = reinterpret_cast<const unsigned*>(
                        h + (size_t)(lo & 0x1FFFFu) * OUT_CH);
                    hv[j] = hp[lane];
                }
#pragma unroll
                for (int j = 0; j < 16; ++j) {
                    a0 += wt[j] * __builtin_bit_cast(float, hv[j] << 16);
                    a1 += wt[j] * __builtin_bit_cast(float, hv[j] & 0xFFFF0000u);
                }
            }
            if (i < s1p) {   // exactly 8 remaining
                unsigned int hv[8];
                float wt[8];
#pragma unroll
                for (int j = 0; j < 8; ++j) {
                    const unsigned long long rr = sorted[i + j];
                    const unsigned lo = __builtin_amdgcn_readfirstlane((unsigned)rr);
                    const unsigned hi = __builtin_amdgcn_readfirstlane((unsigned)(rr >> 32));
                    wt[j] = __builtin_bit_cast(float, hi & 0xFFFF0000u);
                    const unsigned* hp = reinterpret_cast<const unsigned*>(
                        h + (size_t)(lo & 0x1FFFFu) * OUT_CH);
                    hv[j] = hp[lane];
                }
#pragma unroll
                for (int j = 0; j < 8; ++j) {
                    a0 += wt[j] * __builtin_bit_cast(float, hv[j] << 16);
                    a1 += wt[j] * __builtin_bit_cast(float, hv[j] & 0xFFFF0000u);
                }
            }
            acc[d][0] += a0;
            acc[d][1] += a1;
        }
    }

    // write out: coalesced 8B per lane per dst row
#pragma unroll
    for (int d = 0; d < 16; ++d) {
        const int node = bkt * BKT_SIZE + w * 16 + d;
        if (node < n_nodes) {
            f32x2 v = {acc[d][0], acc[d][1]};
            __builtin_nontemporal_store(
                v, reinterpret_cast<f32x2*>(out + (size_t)node * OUT_CH + 2 * lane));
        }
    }
}

extern "C" void kernel_launch(void* const* d_in, const int* in_sizes, int n_in,
                              void* d_out, int out_size, void* d_ws, size_t ws_size,
                              hipStream_t stream) {
    const float* x           = (const float*)d_in[0];
    const int*   edge_src    = (const int*)d_in[1];
    const int*   edge_dst    = (const int*)d_in[2];
    const float* edge_weight = (const float*)d_in[3];
    const float* W           = (const float*)d_in[4];
    const float* b           = (const float*)d_in[5];
    float* out = (float*)d_out;

    const int n_nodes = in_sizes[0] / IN_CH;
    const int n_edges = in_sizes[1];
    const int nb = (n_nodes + BKT_SIZE - 1) / BKT_SIZE;          // 782
    const int nblk = (n_edges + K3_CHUNK - 1) / K3_CHUNK;        // 196

    // workspace layout
    unsigned long long* records = (unsigned long long*)d_ws;            // E * 8B
    unsigned short* h  = (unsigned short*)(records + n_edges);          // N*128 bf16
    int* bh    = (int*)(h + (size_t)n_nodes * OUT_CH);                  // MAXNB*MAXBLK
    int* offs  = bh + MAXNB * MAXBLK;                                   // MAXNB*MAXBLK
    int* total = offs + MAXNB * MAXBLK;                                 // MAXNB
    int* base  = total + MAXNB;                                         // MAXNB+1
    unsigned short* Wfrag = (unsigned short*)(base + MAXNB + 2);        // 64 KB

    prep_w<<<16, 256, 0, stream>>>(W, Wfrag);
    linear_mfma<<<(n_nodes + 255) / 256, 512, 0, stream>>>(x, Wfrag, b, h, n_nodes);
    k1_hist<<<nblk, 512, 0, stream>>>(edge_dst, bh, n_edges, nb);
    k2a_scan_cols<<<nb, 256, 0, stream>>>(bh, offs, total, nblk);
    k2b_scan_base<<<1, 256, 0, stream>>>(total, base, nb);
    k3_bin<<<nblk, 512, 0, stream>>>(edge_src, edge_dst, edge_weight,
                                     offs, base, records, n_edges, nb);
    k4_agg<<<nb, 512, 0, stream>>>(h, records, base, out, n_nodes);
}

// Round 13
// 130.619 us; speedup vs baseline: 1.1681x; 1.1681x over previous
//
#include <hip/hip_runtime.h>
#include <hip/hip_bf16.h>

#define IN_CH 256
#define OUT_CH 128
#define BKT_SHIFT 7                 // 128 dst nodes per bucket
#define BKT_SIZE 128
#define BSUB 64                     // k4 half-bucket (dsts per block)
#define MAXNB 1024                  // bucket-count cap
#define K3_CHUNK 8192
#define MAXBLK 256                  // bin blocks cap
#define BATCH 3072                  // k4 records per batch (6 regs * 512 threads)
#define CAPP 4096                   // k4 padded LDS capacity

using bf16x8 = __attribute__((ext_vector_type(8))) __bf16;
using f32x16 = __attribute__((ext_vector_type(16))) float;
using f32x4  = __attribute__((ext_vector_type(4))) float;
using f32x2  = __attribute__((ext_vector_type(2))) float;

__device__ __forceinline__ unsigned int f2bf(float f) {
    union { float f; unsigned u; } v; v.f = f;
    unsigned r = v.u + 0x7fffu + ((v.u >> 16) & 1u);
    return r >> 16;
}
__device__ __forceinline__ float bf2f(unsigned short u) {
    union { unsigned u; float f; } v; v.u = ((unsigned)u) << 16;
    return v.f;
}

// ---------------- prep_w: W (f32 [128][256]) -> bf16 MFMA B-fragment order ----------------
__global__ void __launch_bounds__(256) prep_w(const float* __restrict__ W,
                                              unsigned short* __restrict__ Wfrag) {
    const int flat = blockIdx.x * 256 + threadIdx.x;  // 0..4095
    const int l = flat & 63;
    const int ks = (flat >> 6) & 15;
    const int c = flat >> 10;
    const int row = c * 32 + (l & 31);
    const int col0 = ks * 16 + 8 * (l >> 5);
    const float* src = W + (size_t)row * IN_CH + col0;
    uint4 o;
    o.x = f2bf(src[0]) | (f2bf(src[1]) << 16);
    o.y = f2bf(src[2]) | (f2bf(src[3]) << 16);
    o.z = f2bf(src[4]) | (f2bf(src[5]) << 16);
    o.w = f2bf(src[6]) | (f2bf(src[7]) << 16);
    *reinterpret_cast<uint4*>(Wfrag + (size_t)flat * 8) = o;
}

// ---------------- linear: h = bf16(x @ W.T + b); Wfrag staged in LDS ----------------
__global__ void __launch_bounds__(512) linear_mfma(
    const float* __restrict__ x, const unsigned short* __restrict__ Wfrag,
    const float* __restrict__ b, unsigned short* __restrict__ h, int n_nodes) {
    __shared__ uint4 wlds[4096];     // 64 KB: full Wfrag in fragment order
    const int tid = threadIdx.x;
    const int w = tid >> 6, l = tid & 63;
    const int l31 = l & 31, lh = l >> 5;
    const int node0 = blockIdx.x * 256 + w * 32;

    {
        const uint4* wfg = reinterpret_cast<const uint4*>(Wfrag);
#pragma unroll
        for (int j = 0; j < 8; ++j) wlds[j * 512 + tid] = wfg[j * 512 + tid];
    }
    __syncthreads();

    int arow = node0 + l31;
    if (arow > n_nodes - 1) arow = n_nodes - 1;
    const float* xrow = x + (size_t)arow * IN_CH + 8 * lh;

    f32x16 acc0 = {}, acc1 = {}, acc2 = {}, acc3 = {};

#pragma unroll 4
    for (int ks = 0; ks < 16; ++ks) {
        float4 a0 = *reinterpret_cast<const float4*>(xrow + ks * 16);
        float4 a1 = *reinterpret_cast<const float4*>(xrow + ks * 16 + 4);
        bf16x8 af;
        af[0] = (__bf16)a0.x; af[1] = (__bf16)a0.y;
        af[2] = (__bf16)a0.z; af[3] = (__bf16)a0.w;
        af[4] = (__bf16)a1.x; af[5] = (__bf16)a1.y;
        af[6] = (__bf16)a1.z; af[7] = (__bf16)a1.w;

        uint4 bw0 = wlds[(0 * 16 + ks) * 64 + l];
        uint4 bw1 = wlds[(1 * 16 + ks) * 64 + l];
        uint4 bw2 = wlds[(2 * 16 + ks) * 64 + l];
        uint4 bw3 = wlds[(3 * 16 + ks) * 64 + l];

        acc0 = __builtin_amdgcn_mfma_f32_32x32x16_bf16(af, __builtin_bit_cast(bf16x8, bw0), acc0, 0, 0, 0);
        acc1 = __builtin_amdgcn_mfma_f32_32x32x16_bf16(af, __builtin_bit_cast(bf16x8, bw1), acc1, 0, 0, 0);
        acc2 = __builtin_amdgcn_mfma_f32_32x32x16_bf16(af, __builtin_bit_cast(bf16x8, bw2), acc2, 0, 0, 0);
        acc3 = __builtin_amdgcn_mfma_f32_32x32x16_bf16(af, __builtin_bit_cast(bf16x8, bw3), acc3, 0, 0, 0);
    }

    const float bias0 = b[0 + l31], bias1 = b[32 + l31], bias2 = b[64 + l31], bias3 = b[96 + l31];
#pragma unroll
    for (int reg = 0; reg < 16; ++reg) {
        const int r = (reg & 3) + 8 * (reg >> 2) + 4 * lh;
        const int node = node0 + r;
        if (node < n_nodes) {
            unsigned short* hp = h + (size_t)node * OUT_CH;
            __bf16 t0 = (__bf16)(acc0[reg] + bias0);
            __bf16 t1 = (__bf16)(acc1[reg] + bias1);
            __bf16 t2 = (__bf16)(acc2[reg] + bias2);
            __bf16 t3 = (__bf16)(acc3[reg] + bias3);
            hp[0 + l31]  = __builtin_bit_cast(unsigned short, t0);
            hp[32 + l31] = __builtin_bit_cast(unsigned short, t1);
            hp[64 + l31] = __builtin_bit_cast(unsigned short, t2);
            hp[96 + l31] = __builtin_bit_cast(unsigned short, t3);
        }
    }
}

// ---------------- K1: per-block bucket histogram (LDS, no global atomics) ----------------
__global__ void __launch_bounds__(512) k1_hist(
    const int* __restrict__ edge_dst, int* __restrict__ bh, int n_edges, int nb) {
    __shared__ int hist[MAXNB];
    const int t = threadIdx.x;
    const int blk = blockIdx.x;
    for (int i = t; i < MAXNB; i += 512) hist[i] = 0;
    __syncthreads();
    const int base = blk * K3_CHUNK;
#pragma unroll
    for (int j = 0; j < K3_CHUNK / 512; ++j) {
        int e = base + j * 512 + t;
        if (e < n_edges) atomicAdd(&hist[edge_dst[e] >> BKT_SHIFT], 1);
    }
    __syncthreads();
    for (int i = t; i < nb; i += 512) bh[i * MAXBLK + blk] = hist[i];
}

// ---------------- K2a: per-bucket exclusive scan over blocks ----------------
__global__ void __launch_bounds__(256) k2a_scan_cols(
    const int* __restrict__ bh, int* __restrict__ offs, int* __restrict__ total,
    int nblk) {
    __shared__ int sd[256];
    const int t = threadIdx.x;
    const int bkt = blockIdx.x;
    int val = (t < nblk) ? bh[bkt * MAXBLK + t] : 0;
    sd[t] = val;
    __syncthreads();
    for (int s = 1; s < 256; s <<= 1) {
        int y = (t >= s) ? sd[t - s] : 0;
        __syncthreads();
        sd[t] += y;
        __syncthreads();
    }
    offs[bkt * MAXBLK + t] = sd[t] - val;
    if (t == 255) total[bkt] = sd[255];
}

// ---------------- K2b: exclusive scan over bucket totals -> base ----------------
__global__ void __launch_bounds__(256) k2b_scan_base(
    const int* __restrict__ total, int* __restrict__ base, int nb) {
    __shared__ int sd[256];
    const int t = threadIdx.x;
    int v[4];
    int loc = 0;
#pragma unroll
    for (int k = 0; k < 4; ++k) {
        int idx = t * 4 + k;
        v[k] = (idx < nb) ? total[idx] : 0;
        loc += v[k];
    }
    sd[t] = loc;
    __syncthreads();
    for (int s = 1; s < 256; s <<= 1) {
        int y = (t >= s) ? sd[t - s] : 0;
        __syncthreads();
        sd[t] += y;
        __syncthreads();
    }
    int run = sd[t] - loc;
#pragma unroll
    for (int k = 0; k < 4; ++k) {
        int idx = t * 4 + k;
        if (idx < nb) base[idx] = run;
        run += v[k];
    }
    if (t == 255) base[nb] = sd[255];
}

// ---------------- K3: chunk counting-sort by bucket, coalesced record write ----------------
// record u64: [w_bf16:48-63 | bucket:24-33 | dst&127:17-23 | src:0-16]
__global__ void __launch_bounds__(512) k3_bin(
    const int* __restrict__ edge_src, const int* __restrict__ edge_dst,
    const float* __restrict__ edge_weight,
    const int* __restrict__ offs, const int* __restrict__ base,
    unsigned long long* __restrict__ records, int n_edges, int nb) {
    __shared__ unsigned long long staged[K3_CHUNK];
    __shared__ int hist[MAXNB];
    __shared__ int cur[MAXNB];
    __shared__ int gbase[MAXNB];
    __shared__ int sd[512];

    const int t = threadIdx.x;
    const int blk = blockIdx.x;
    const int ebase = blk * K3_CHUNK;
    const int count = min(K3_CHUNK, n_edges - ebase);

    for (int i = t; i < MAXNB; i += 512) hist[i] = 0;
    __syncthreads();
#pragma unroll
    for (int j = 0; j < K3_CHUNK / 512; ++j) {
        int e = ebase + j * 512 + t;
        if (e < n_edges) atomicAdd(&hist[edge_dst[e] >> BKT_SHIFT], 1);
    }
    __syncthreads();
    int h0 = hist[2 * t], h1 = hist[2 * t + 1];
    int loc = h0 + h1;
    sd[t] = loc;
    __syncthreads();
    for (int s = 1; s < 512; s <<= 1) {
        int y = (t >= s) ? sd[t - s] : 0;
        __syncthreads();
        sd[t] += y;
        __syncthreads();
    }
    int excl = sd[t] - loc;
    cur[2 * t] = excl;
    cur[2 * t + 1] = excl + h0;
    if (2 * t < nb)     gbase[2 * t]     = base[2 * t]     + offs[(2 * t) * MAXBLK + blk]     - excl;
    if (2 * t + 1 < nb) gbase[2 * t + 1] = base[2 * t + 1] + offs[(2 * t + 1) * MAXBLK + blk] - (excl + h0);
    __syncthreads();
#pragma unroll
    for (int j = 0; j < K3_CHUNK / 512; ++j) {
        int e = ebase + j * 512 + t;
        if (e < n_edges) {
            int d = edge_dst[e];
            int bkt = d >> BKT_SHIFT;
            unsigned int wbits = f2bf(edge_weight[e]);   // bf16 bits
            unsigned long long rec = ((unsigned long long)wbits << 48) |
                                     ((unsigned long long)bkt << 24) |
                                     ((unsigned long long)(d & (BKT_SIZE - 1)) << 17) |
                                     (unsigned int)edge_src[e];
            int pos = atomicAdd(&cur[bkt], 1);
            staged[pos] = rec;
        }
    }
    __syncthreads();
    for (int i = t; i < count; i += 512) {
        unsigned long long r = staged[i];
        int bkt = (int)((r >> 24) & 1023u);
        records[gbase[bkt] + i] = r;
    }
}

// ---------------- K4: half-bucket dst-sort (regs->LDS, 8-padded) + 8-deep gather -------
// grid = nb*2; block (bkt, sub) owns dsts [bkt*128 + sub*64, +64).
// 512 threads = 8 waves; wave w owns 8 dst rows; lane owns channels 2l, 2l+1.
__global__ void __launch_bounds__(512) k4_agg(
    const unsigned short* __restrict__ h, const unsigned long long* __restrict__ records,
    const int* __restrict__ base, float* __restrict__ out, int n_nodes) {
    __shared__ unsigned long long sorted[CAPP];   // 32 KB
    __shared__ int hist[BSUB];
    __shared__ int cur[BSUB];
    __shared__ int pstart[BSUB];
    __shared__ int sd[BSUB];
    __shared__ int ptot;

    const int t = threadIdx.x;
    const int bkt = blockIdx.x >> 1;
    const int sub = blockIdx.x & 1;
    const int w = t >> 6, lane = t & 63;
    const int rbeg = base[bkt], rend = base[bkt + 1];

    float acc[8][2];
#pragma unroll
    for (int d = 0; d < 8; ++d) { acc[d][0] = 0.f; acc[d][1] = 0.f; }

    for (int b0 = rbeg; b0 < rend; b0 += BATCH) {
        const int cnt = min(BATCH, rend - b0);
        __syncthreads();  // previous batch fully consumed
        // stage records into registers (coalesced)
        unsigned long long r[6];
        int keep[6];
#pragma unroll
        for (int j = 0; j < 6; ++j) {
            const int o = j * 512 + t;
            r[j] = (o < cnt) ? records[b0 + o] : 0ull;
            const int dl7 = (int)((unsigned)(r[j] >> 17) & 127u);
            keep[j] = (o < cnt) && ((dl7 >> 6) == sub);
        }
        if (t < BSUB) hist[t] = 0;
        __syncthreads();
        // histogram by dst-low (this half only)
#pragma unroll
        for (int j = 0; j < 6; ++j)
            if (keep[j]) atomicAdd(&hist[(unsigned)(r[j] >> 17) & 63u], 1);
        __syncthreads();
        // exclusive scan of ceil8(hist) over 64 bins
        if (t < BSUB) sd[t] = (hist[t] + 7) & ~7;
        __syncthreads();
        for (int s = 1; s < BSUB; s <<= 1) {
            int y = 0;
            if (t < BSUB && t >= s) y = sd[t - s];
            __syncthreads();
            if (t < BSUB) sd[t] += y;
            __syncthreads();
        }
        if (t < BSUB) {
            const int e = sd[t] - ((hist[t] + 7) & ~7);
            pstart[t] = e;
            cur[t] = e;
        }
        if (t == BSUB - 1) ptot = sd[BSUB - 1];
        __syncthreads();
        // zero padded region (pad records: w=0, src=0 -> contribute nothing)
        const int pt = ptot;
        for (int i = t; i < pt; i += 512) sorted[i] = 0ull;
        __syncthreads();
        // scatter into dst-sorted order
#pragma unroll
        for (int j = 0; j < 6; ++j) {
            if (keep[j]) {
                const int dl = (int)((unsigned)(r[j] >> 17) & 63u);
                const int pos = atomicAdd(&cur[dl], 1);
                sorted[pos] = r[j];
            }
        }
        __syncthreads();
        // aggregate: wave w handles dl = w*8+d; 8-padded segments, branchless G=8
#pragma unroll
        for (int d = 0; d < 8; ++d) {
            const int dl = w * 8 + d;
            const int s0 = pstart[dl];
            const int s1 = s0 + hist[dl];
            float a0 = 0.f, a1 = 0.f;
            for (int i = s0; i < s1; i += 8) {
                unsigned int hv[8];
                float wt[8];
#pragma unroll
                for (int j = 0; j < 8; ++j) {
                    const unsigned long long rr = sorted[i + j];   // uniform broadcast
                    const unsigned lo = __builtin_amdgcn_readfirstlane((unsigned)rr);
                    const unsigned hi = __builtin_amdgcn_readfirstlane((unsigned)(rr >> 32));
                    wt[j] = __builtin_bit_cast(float, hi & 0xFFFF0000u);
                    const unsigned* hp = reinterpret_cast<const unsigned*>(
                        h + (size_t)(lo & 0x1FFFFu) * OUT_CH);
                    hv[j] = hp[lane];   // global_load_dword v, v_off, s[base]
                }
#pragma unroll
                for (int j = 0; j < 8; ++j) {
                    a0 += wt[j] * __builtin_bit_cast(float, hv[j] << 16);
                    a1 += wt[j] * __builtin_bit_cast(float, hv[j] & 0xFFFF0000u);
                }
            }
            acc[d][0] += a0;
            acc[d][1] += a1;
        }
    }

    // write out: coalesced 8B per lane per dst row
#pragma unroll
    for (int d = 0; d < 8; ++d) {
        const int node = bkt * BKT_SIZE + sub * BSUB + w * 8 + d;
        if (node < n_nodes) {
            f32x2 v = {acc[d][0], acc[d][1]};
            __builtin_nontemporal_store(
                v, reinterpret_cast<f32x2*>(out + (size_t)node * OUT_CH + 2 * lane));
        }
    }
}

extern "C" void kernel_launch(void* const* d_in, const int* in_sizes, int n_in,
                              void* d_out, int out_size, void* d_ws, size_t ws_size,
                              hipStream_t stream) {
    const float* x           = (const float*)d_in[0];
    const int*   edge_src    = (const int*)d_in[1];
    const int*   edge_dst    = (const int*)d_in[2];
    const float* edge_weight = (const float*)d_in[3];
    const float* W           = (const float*)d_in[4];
    const float* b           = (const float*)d_in[5];
    float* out = (float*)d_out;

    const int n_nodes = in_sizes[0] / IN_CH;
    const int n_edges = in_sizes[1];
    const int nb = (n_nodes + BKT_SIZE - 1) / BKT_SIZE;          // 782
    const int nblk = (n_edges + K3_CHUNK - 1) / K3_CHUNK;        // 196

    // workspace layout
    unsigned long long* records = (unsigned long long*)d_ws;            // E * 8B
    unsigned short* h  = (unsigned short*)(records + n_edges);          // N*128 bf16
    int* bh    = (int*)(h + (size_t)n_nodes * OUT_CH);                  // MAXNB*MAXBLK
    int* offs  = bh + MAXNB * MAXBLK;                                   // MAXNB*MAXBLK
    int* total = offs + MAXNB * MAXBLK;                                 // MAXNB
    int* base  = total + MAXNB;                                         // MAXNB+1
    unsigned short* Wfrag = (unsigned short*)(base + MAXNB + 2);        // 64 KB

    prep_w<<<16, 256, 0, stream>>>(W, Wfrag);
    linear_mfma<<<(n_nodes + 255) / 256, 512, 0, stream>>>(x, Wfrag, b, h, n_nodes);
    k1_hist<<<nblk, 512, 0, stream>>>(edge_dst, bh, n_edges, nb);
    k2a_scan_cols<<<nb, 256, 0, stream>>>(bh, offs, total, nblk);
    k2b_scan_base<<<1, 256, 0, stream>>>(total, base, nb);
    k3_bin<<<nblk, 512, 0, stream>>>(edge_src, edge_dst, edge_weight,
                                     offs, base, records, n_edges, nb);
    k4_agg<<<nb * 2, 512, 0, stream>>>(h, records, base, out, n_nodes);
}